// Round 6
// baseline (282.551 us; speedup 1.0000x reference)
//
#include <hip/hip_runtime.h>
#include <hip/hip_bf16.h>
#include <stdint.h>

#define IN_F 4096
#define OUT_F 11008
#define TOKENS 32
#define NELEM_W (OUT_F * IN_F)       // 45088768 weights, ~180 MB fp32
#define OUT_ELEMS (TOKENS * OUT_F)   // 352256
#define NBLK 688                     // OUT_F / 16

typedef __attribute__((ext_vector_type(8))) __bf16 bf16x8;
typedef __attribute__((ext_vector_type(4))) float  f32x4;

// d_ws layout (bytes):
//   [0, 4096):        apart — 688 per-block |w| partial sums (f32)
//   [4096, +256K):    xb   — x converted to bf16
#define APART_OFF 0
#define XB_OFF    4096

// fp32 -> bf16 bits (round-to-nearest-even), result in low 16
__device__ __forceinline__ uint32_t bfr(float v) {
    uint32_t u = __float_as_uint(v);
    uint32_t r = u + 0x7FFFu + ((u >> 16) & 1u);
    return r >> 16;
}

// ---------------- kernel A: per-rowgroup |w| partials + x->bf16 ----------------
// Block b sums rows [16b, 16b+16) — exactly the rows kernel B's block b will
// use, so w is L3-resident (172 MiB < 256 MiB) when B runs.
__global__ __launch_bounds__(256) void absum_xcvt_kernel(const float* __restrict__ w,
                                                         const float* __restrict__ x,
                                                         float* __restrict__ apart,
                                                         uint4* __restrict__ xb) {
    const int tid = threadIdx.x;
    if (blockIdx.x < 64) {
        // x conversion: 64 blocks x 256 threads, 8 floats each = 131072 floats
        int i = blockIdx.x * 256 + tid;
        const float4* x4 = (const float4*)x;
        float4 a0 = x4[i * 2];
        float4 a1 = x4[i * 2 + 1];
        uint4 o;
        o.x = bfr(a0.x) | (bfr(a0.y) << 16);
        o.y = bfr(a0.z) | (bfr(a0.w) << 16);
        o.z = bfr(a1.x) | (bfr(a1.y) << 16);
        o.w = bfr(a1.z) | (bfr(a1.w) << 16);
        xb[i] = o;
    }
    // abs-sum of this block's 16 w rows (65536 floats = 16384 float4)
    const float4* wb4 = (const float4*)(w + (size_t)blockIdx.x * (16 * IN_F));
    float s = 0.f;
#pragma unroll 4
    for (int i = tid; i < 16384; i += 256) {
        float4 v = wb4[i];
        s += fabsf(v.x) + fabsf(v.y) + fabsf(v.z) + fabsf(v.w);
    }
    for (int off = 32; off > 0; off >>= 1)
        s += __shfl_down(s, off, 64);
    __shared__ float wsum[4];
    int lane = tid & 63;
    int wv   = tid >> 6;
    if (lane == 0) wsum[wv] = s;
    __syncthreads();
    if (tid == 0)
        apart[blockIdx.x] = wsum[0] + wsum[1] + wsum[2] + wsum[3];
}

// ---------------- ternarize helpers (verified R5 math) ----------------
__device__ __forceinline__ uint32_t tern1(float v, float thr) {
    uint32_t u  = __float_as_uint(v);
    uint32_t pm = (u & 0x80000000u) | 0x3F800000u;   // +-1.0f
    return (__builtin_fabsf(v) > thr) ? pm : 0u;
}

__device__ __forceinline__ uint2 tern4(float4 b, float thr) {
    uint32_t q0 = tern1(b.x, thr), q1 = tern1(b.y, thr);
    uint32_t q2 = tern1(b.z, thr), q3 = tern1(b.w, thr);
    uint2 r;
    r.x = __builtin_amdgcn_perm(q1, q0, 0x07060302u);
    r.y = __builtin_amdgcn_perm(q3, q2, 0x07060302u);
    return r;
}

// ---------------- kernel B: threshold + LDS-staged ternary GEMM ----------------
// 688 blocks x 256 threads (4 waves), block og owns out cols [og*16, +16).
// Stage 1: every block reduces the 688 partials -> thr/scale (no serializing
//   finalize dispatch). Stage 2: wave wv covers k in [wv*1024, +1024),
//   16 chunks of 64, 2-deep register double-buffer, per-wave LDS staging
//   (row stride 144 B). Stage 3: 4-wave LDS reduce, direct store to out.
#define CHUNKS 16
#define WAVE_LDS 2304          // 16 rows * 144 B
#define SMEM_BYTES 9216        // 4 waves staging; also covers 4*512*4 reduce

__global__ __launch_bounds__(256, 4) void ternary_gemm(const float* __restrict__ w,
                                                       const float* __restrict__ apart,
                                                       const __bf16* __restrict__ xb,
                                                       float* __restrict__ out) {
    __shared__ char smem_raw[SMEM_BYTES];
    const int og   = blockIdx.x;
    const int tid  = threadIdx.x;
    const int wv   = tid >> 6;
    const int lane = tid & 63;
    const int col  = lane & 15;     // fragment: output col in group / token
    const int quad = lane >> 4;     // fragment k sub-block; staging row group
    const int rlan = lane & 15;     // staging: 16-B slot within a row

    // ---- stage 1: threshold from partials ----
    float s = 0.f;
    for (int j = tid; j < NBLK; j += 256) s += apart[j];
    for (int off = 32; off > 0; off >>= 1)
        s += __shfl_down(s, off, 64);
    float* sred = (float*)smem_raw;
    if (lane == 0) sred[wv] = s;
    __syncthreads();
    if (tid == 0) {
        double mean = (double)(sred[0] + sred[1] + sred[2] + sred[3]) / (double)NELEM_W;
        if (mean < 1e-5) mean = 1e-5;
        float mf = (float)mean;
        sred[4] = 0.7f * mf;
        sred[5] = mf;
    }
    __syncthreads();
    const float thr   = sred[4];
    const float scale = sred[5];
    __syncthreads();   // done reading sred before staging overwrites it

    // ---- stage 2: GEMM over K, 1024 per wave ----
    const int kw = wv * 1024;
    const float* wp = w + (size_t)(og * 16 + quad) * IN_F + kw + rlan * 4;
    char* stage = smem_raw + wv * WAVE_LDS;
    char* wr    = stage + quad * 144 + rlan * 8;   // + j*576 per staging instr
    const char* rd = stage + col * 144;
    const __bf16* xq = xb + (size_t)col * IN_F + kw + quad * 8;

    f32x4 acc0 = {0.f, 0.f, 0.f, 0.f};
    f32x4 acc1 = {0.f, 0.f, 0.f, 0.f};

    float4 wb[2][4];
    bf16x8 xv[2][4];

#pragma unroll
    for (int c = 0; c < 2; ++c) {
        const float*  np = wp + c * 64;
        const __bf16* xn = xq + c * 64;
        wb[c][0] = *(const float4*)(np);
        wb[c][1] = *(const float4*)(np + 4 * IN_F);
        wb[c][2] = *(const float4*)(np + 8 * IN_F);
        wb[c][3] = *(const float4*)(np + 12 * IN_F);
        xv[c][0] = *(const bf16x8*)(xn);
        xv[c][1] = *(const bf16x8*)(xn + 32);
        xv[c][2] = *(const bf16x8*)(xn + 16 * IN_F);
        xv[c][3] = *(const bf16x8*)(xn + 16 * IN_F + 32);
    }

#define GEMM_BODY(c, cur)                                                      \
    {                                                                          \
        uint2 t0 = tern4(wb[cur][0], thr);                                     \
        uint2 t1 = tern4(wb[cur][1], thr);                                     \
        uint2 t2 = tern4(wb[cur][2], thr);                                     \
        uint2 t3 = tern4(wb[cur][3], thr);                                     \
        *(uint2*)(wr)        = t0;                                             \
        *(uint2*)(wr + 576)  = t1;                                             \
        *(uint2*)(wr + 1152) = t2;                                             \
        *(uint2*)(wr + 1728) = t3;                                             \
        bf16x8 a00 = xv[cur][0], a01 = xv[cur][1];                             \
        bf16x8 a10 = xv[cur][2], a11 = xv[cur][3];                             \
        if ((c) + 2 < CHUNKS) {                                                \
            const float*  np = wp + ((c) + 2) * 64;                            \
            const __bf16* xn = xq + ((c) + 2) * 64;                            \
            wb[cur][0] = *(const float4*)(np);                                 \
            wb[cur][1] = *(const float4*)(np + 4 * IN_F);                      \
            wb[cur][2] = *(const float4*)(np + 8 * IN_F);                      \
            wb[cur][3] = *(const float4*)(np + 12 * IN_F);                     \
            xv[cur][0] = *(const bf16x8*)(xn);                                 \
            xv[cur][1] = *(const bf16x8*)(xn + 32);                            \
            xv[cur][2] = *(const bf16x8*)(xn + 16 * IN_F);                     \
            xv[cur][3] = *(const bf16x8*)(xn + 16 * IN_F + 32);                \
        }                                                                      \
        bf16x8 bw0 = *(const bf16x8*)(rd + quad * 16);                         \
        bf16x8 bw1 = *(const bf16x8*)(rd + 64 + quad * 16);                    \
        acc0 = __builtin_amdgcn_mfma_f32_16x16x32_bf16(a00, bw0, acc0, 0, 0, 0); \
        acc1 = __builtin_amdgcn_mfma_f32_16x16x32_bf16(a10, bw0, acc1, 0, 0, 0); \
        acc0 = __builtin_amdgcn_mfma_f32_16x16x32_bf16(a01, bw1, acc0, 0, 0, 0); \
        acc1 = __builtin_amdgcn_mfma_f32_16x16x32_bf16(a11, bw1, acc1, 0, 0, 0); \
    }

    for (int c = 0; c < CHUNKS; c += 2) {
        GEMM_BODY(c, 0)
        GEMM_BODY(c + 1, 1)
    }
#undef GEMM_BODY

    // ---- stage 3: 4-wave reduce, direct store ----
    __syncthreads();
    float* red  = (float*)smem_raw;
    float* base = red + wv * 512;
#pragma unroll
    for (int r = 0; r < 4; ++r) base[r * 64 + lane]       = acc0[r];
#pragma unroll
    for (int r = 0; r < 4; ++r) base[256 + r * 64 + lane] = acc1[r];
    __syncthreads();

#pragma unroll
    for (int p = tid; p < 512; p += 256) {
        int t = p >> 4, cc = p & 15;
        int a = t >> 4;
        int q = (t >> 2) & 3;
        int r = t & 3;
        int idx = a * 256 + r * 64 + q * 16 + cc;
        float v = red[idx] + red[512 + idx] + red[1024 + idx] + red[1536 + idx];
        out[(size_t)t * OUT_F + og * 16 + cc] = v * scale;
    }
}

extern "C" void kernel_launch(void* const* d_in, const int* in_sizes, int n_in,
                              void* d_out, int out_size, void* d_ws, size_t ws_size,
                              hipStream_t stream) {
    const float* x = (const float*)d_in[0];   // [32, 4096]
    const float* w = (const float*)d_in[1];   // [11008, 4096]
    float* out     = (float*)d_out;           // [32, 11008]
    char* ws       = (char*)d_ws;

    float* apart   = (float*)(ws + APART_OFF);
    uint4* xb      = (uint4*)(ws + XB_OFF);

    absum_xcvt_kernel<<<NBLK, 256, 0, stream>>>(w, x, apart, xb);
    ternary_gemm<<<NBLK, 256, 0, stream>>>(w, apart, (const __bf16*)(ws + XB_OFF), out);
}